// Round 15
// baseline (59.649 us; speedup 1.0000x reference)
//
#include <hip/hip_runtime.h>

// Problem constants
#define B_  32
#define L_  2048
#define D_  256
#define T_  64
#define KW  3
#define ROWS  16          // rows per block
#define XROWS 18          // rows + 2 halo

typedef float f32x4 __attribute__((ext_vector_type(4)));
typedef short s16x8 __attribute__((ext_vector_type(8)));
typedef short s16x4 __attribute__((ext_vector_type(4)));

__device__ __forceinline__ short f2bf(float f) {
    unsigned u = __builtin_bit_cast(unsigned, f);
    u += 0x7FFFu + ((u >> 16) & 1u);          // round-to-nearest-even
    return (short)(u >> 16);
}
__device__ __forceinline__ float bf2f(short s) {
    unsigned u = ((unsigned)(unsigned short)s) << 16;
    return __builtin_bit_cast(float, u);
}

// ---------------------------------------------------------------------------
// fused prep (one launch):
//  bx <  16 : CbfPk = bf16(C) packed in phase-1 B-fragment order
//  bx >= 16 : kcPk = packed relu(C@W+b) in phase-2 B-fragment order
// ---------------------------------------------------------------------------
__global__ __launch_bounds__(256) void prep_kernel(const float* __restrict__ C,
                                                   const float* __restrict__ W,
                                                   const float* __restrict__ bias,
                                                   short* __restrict__ CbfPk,
                                                   short* __restrict__ kcPk) {
    __shared__ float Ws[256 * 16];
    const int tid = threadIdx.x;

    if (blockIdx.x < 16) {
        const int i0 = (blockIdx.x * 256 + tid) * 4;
        const int t = i0 >> 8, d = i0 & 255;
        const f32x4 v = *(const f32x4*)(C + i0);
        s16x4 s;
        s[0] = f2bf(v[0]); s[1] = f2bf(v[1]); s[2] = f2bf(v[2]); s[3] = f2bf(v[3]);
        const int tt = t >> 4, c = t & 15, ks = d >> 5, gg = (d >> 3) & 3, e = d & 7;
        *(s16x4*)&CbfPk[(((tt * 8 + ks) * 4 + gg) * 16 + c) * 8 + e] = s;
        return;
    }

    const int nb = blockIdx.x - 16;
    const int n0 = nb * 16;

    for (int idx = tid; idx < 256 * 16; idx += 256) {
        const int dd = idx >> 4, nl = idx & 15;
        Ws[idx] = W[dd * (KW * D_) + n0 + nl];
    }
    __syncthreads();

    const int t  = tid >> 2;
    const int nl = tid & 3;
    float acc[4];
    #pragma unroll
    for (int i = 0; i < 4; ++i) acc[i] = bias[n0 + nl + 4 * i];

    const float* Crow = C + t * D_;
    for (int dd = 0; dd < D_; ++dd) {
        const float cv = Crow[dd];
        #pragma unroll
        for (int i = 0; i < 4; ++i)
            acc[i] = fmaf(cv, Ws[dd * 16 + nl + 4 * i], acc[i]);
    }
    const int ks = t >> 5, gg = (t >> 3) & 3, e = t & 7;
    #pragma unroll
    for (int i = 0; i < 4; ++i) {
        const int cc = nl + 4 * i;
        kcPk[(((nb * 2 + ks) * 4 + gg) * 16 + cc) * 8 + e] = f2bf(fmaxf(acc[i], 0.f));
    }
}

// ---------------------------------------------------------------------------
// main: R6 structure x 2 BATCHES per block (same l0): every constant
// fragment (CbfPk, kcPk) is loaded once and used for both batches ->
// L2 constant stream halves (524 -> 262 MB). Grid = 128 x 16 = 2048 blocks
// (exactly 8/CU demand, whole grid co-resident).
// LDS = 2*xs (18x264) + 2*atts (16x72) = 23.3 KB -> 6 blocks/CU.
// ---------------------------------------------------------------------------
#define XST 264
#define ATS 72

__global__ __launch_bounds__(256, 6) void main_kernel(const float* __restrict__ x,
                                                      const short* __restrict__ CbfPk,
                                                      const short* __restrict__ kcPk,
                                                      float* __restrict__ out) {
    __shared__ short xs0[XROWS * XST];     // 9504 B
    __shared__ short xs1[XROWS * XST];     // 9504 B
    __shared__ short atts0[ROWS * ATS];    // 2304 B
    __shared__ short atts1[ROWS * ATS];    // 2304 B

    const int tid  = threadIdx.x;
    const int w    = tid >> 6;        // wave 0..3
    const int lane = tid & 63;
    const int c    = lane & 15;
    const int g    = lane >> 4;
    const int l0   = blockIdx.x * ROWS;
    const int b0   = blockIdx.y * 2;

    // ---- stage both batches' x rows l0-1 .. l0+16 as bf16 ----
    const f32x4* x4a = (const f32x4*)(x + (size_t)b0 * L_ * D_);
    const f32x4* x4b = (const f32x4*)(x + (size_t)(b0 + 1) * L_ * D_);
    for (int idx = tid; idx < 2 * XROWS * 64; idx += 256) {
        const int bb  = idx >= XROWS * 64;
        const int rem = bb ? idx - XROWS * 64 : idx;
        const int row = rem >> 6;
        const int d4  = rem & 63;
        const int l   = l0 - 1 + row;
        f32x4 v = {0.f, 0.f, 0.f, 0.f};
        if (l >= 0 && l < L_) v = (bb ? x4b : x4a)[(size_t)l * 64 + d4];
        s16x4 s;
        s[0] = f2bf(v[0]); s[1] = f2bf(v[1]); s[2] = f2bf(v[2]); s[3] = f2bf(v[3]);
        *(s16x4*)&(bb ? xs1 : xs0)[row * XST + d4 * 4] = s;
    }
    __syncthreads();

    // ---- phase 1: wave w, t-tile w, both batches; C-frags loaded once ----
    {
        f32x4 acc0 = (f32x4){0.f, 0.f, 0.f, 0.f};
        f32x4 acc1 = (f32x4){0.f, 0.f, 0.f, 0.f};
        const short* xr0 = &xs0[(1 + c) * XST];
        const short* xr1 = &xs1[(1 + c) * XST];
        #pragma unroll
        for (int ks = 0; ks < 8; ++ks) {
            const s16x8 cb = *(const s16x8*)&CbfPk[(((w * 8 + ks) * 4 + g) * 16 + c) * 8];
            const s16x8 a0 = *(const s16x8*)&xr0[ks * 32 + g * 8];
            const s16x8 a1 = *(const s16x8*)&xr1[ks * 32 + g * 8];
            acc0 = __builtin_amdgcn_mfma_f32_16x16x32_bf16(a0, cb, acc0, 0, 0, 0);
            acc1 = __builtin_amdgcn_mfma_f32_16x16x32_bf16(a1, cb, acc1, 0, 0, 0);
        }
        // D layout: col=lane&15 (t), row=(lane>>4)*4+reg (l)
        #pragma unroll
        for (int r = 0; r < 4; ++r) {
            atts0[(g * 4 + r) * ATS + w * 16 + c] = f2bf(acc0[r]);
            atts1[(g * 4 + r) * ATS + w * 16 + c] = f2bf(acc1[r]);
        }
    }
    __syncthreads();

    // ---- phase 2: B-frags loaded once per dtl, used for both batches ----
    const s16x8 af00 = *(const s16x8*)&atts0[c * ATS + 0 * 32 + g * 8];
    const s16x8 af01 = *(const s16x8*)&atts0[c * ATS + 1 * 32 + g * 8];
    const s16x8 af10 = *(const s16x8*)&atts1[c * ATS + 0 * 32 + g * 8];
    const s16x8 af11 = *(const s16x8*)&atts1[c * ATS + 1 * 32 + g * 8];

    const size_t outBase0 = ((size_t)b0 * L_ + l0) * D_;
    const size_t outBase1 = ((size_t)(b0 + 1) * L_ + l0) * D_;

    #pragma unroll
    for (int dtl = 0; dtl < 4; ++dtl) {
        const int dcol = w * 64 + dtl * 16 + c;
        const int nbb  = w * 4 + dtl;        // nb = j*16 + nbb
        const s16x8 kb0 = *(const s16x8*)&kcPk[((((0 * 16 + nbb) * 2 + 0) * 4 + g) * 16 + c) * 8];
        const s16x8 kb1 = *(const s16x8*)&kcPk[((((0 * 16 + nbb) * 2 + 1) * 4 + g) * 16 + c) * 8];
        const s16x8 kb2 = *(const s16x8*)&kcPk[((((1 * 16 + nbb) * 2 + 0) * 4 + g) * 16 + c) * 8];
        const s16x8 kb3 = *(const s16x8*)&kcPk[((((1 * 16 + nbb) * 2 + 1) * 4 + g) * 16 + c) * 8];
        const s16x8 kb4 = *(const s16x8*)&kcPk[((((2 * 16 + nbb) * 2 + 0) * 4 + g) * 16 + c) * 8];
        const s16x8 kb5 = *(const s16x8*)&kcPk[((((2 * 16 + nbb) * 2 + 1) * 4 + g) * 16 + c) * 8];

        // ---- batch 0 ----
        {
            f32x4 a0 = (f32x4){0.f,0.f,0.f,0.f};
            f32x4 a1 = (f32x4){0.f,0.f,0.f,0.f};
            f32x4 a2 = (f32x4){0.f,0.f,0.f,0.f};
            a0 = __builtin_amdgcn_mfma_f32_16x16x32_bf16(af00, kb0, a0, 0, 0, 0);
            a0 = __builtin_amdgcn_mfma_f32_16x16x32_bf16(af01, kb1, a0, 0, 0, 0);
            a1 = __builtin_amdgcn_mfma_f32_16x16x32_bf16(af00, kb2, a1, 0, 0, 0);
            a1 = __builtin_amdgcn_mfma_f32_16x16x32_bf16(af01, kb3, a1, 0, 0, 0);
            a2 = __builtin_amdgcn_mfma_f32_16x16x32_bf16(af00, kb4, a2, 0, 0, 0);
            a2 = __builtin_amdgcn_mfma_f32_16x16x32_bf16(af01, kb5, a2, 0, 0, 0);
            float xv[6];
            #pragma unroll
            for (int i = 0; i < 6; ++i)
                xv[i] = bf2f(xs0[(g * 4 + i) * XST + dcol]);
            #pragma unroll
            for (int r = 0; r < 4; ++r) {
                const float o = a0[r] * xv[r] + a1[r] * xv[r + 1] + a2[r] * xv[r + 2];
                out[outBase0 + (size_t)(g * 4 + r) * D_ + dcol] = o;
            }
        }
        // ---- batch 1 ----
        {
            f32x4 a0 = (f32x4){0.f,0.f,0.f,0.f};
            f32x4 a1 = (f32x4){0.f,0.f,0.f,0.f};
            f32x4 a2 = (f32x4){0.f,0.f,0.f,0.f};
            a0 = __builtin_amdgcn_mfma_f32_16x16x32_bf16(af10, kb0, a0, 0, 0, 0);
            a0 = __builtin_amdgcn_mfma_f32_16x16x32_bf16(af11, kb1, a0, 0, 0, 0);
            a1 = __builtin_amdgcn_mfma_f32_16x16x32_bf16(af10, kb2, a1, 0, 0, 0);
            a1 = __builtin_amdgcn_mfma_f32_16x16x32_bf16(af11, kb3, a1, 0, 0, 0);
            a2 = __builtin_amdgcn_mfma_f32_16x16x32_bf16(af10, kb4, a2, 0, 0, 0);
            a2 = __builtin_amdgcn_mfma_f32_16x16x32_bf16(af11, kb5, a2, 0, 0, 0);
            float xv[6];
            #pragma unroll
            for (int i = 0; i < 6; ++i)
                xv[i] = bf2f(xs1[(g * 4 + i) * XST + dcol]);
            #pragma unroll
            for (int r = 0; r < 4; ++r) {
                const float o = a0[r] * xv[r] + a1[r] * xv[r + 1] + a2[r] * xv[r + 2];
                out[outBase1 + (size_t)(g * 4 + r) * D_ + dcol] = o;
            }
        }
    }
}

// ---------------------------------------------------------------------------
extern "C" void kernel_launch(void* const* d_in, const int* in_sizes, int n_in,
                              void* d_out, int out_size, void* d_ws, size_t ws_size,
                              hipStream_t stream) {
    const float* x    = (const float*)d_in[0];
    const float* C    = (const float*)d_in[1];
    const float* Wden = (const float*)d_in[2];
    const float* bden = (const float*)d_in[3];
    float* out = (float*)d_out;

    short* kcPk  = (short*)d_ws;                   // [768][64] bf16 = 98304 B
    short* CbfPk = (short*)d_ws + KW * D_ * T_;    // [64][256] bf16 = 32768 B

    prep_kernel<<<dim3(64), dim3(256), 0, stream>>>(C, Wden, bden, CbfPk, kcPk);

    dim3 grid(L_ / ROWS, B_ / 2);
    main_kernel<<<grid, dim3(256), 0, stream>>>(x, CbfPk, kcPk, out);
}